// Round 1
// baseline (763.428 us; speedup 1.0000x reference)
//
#include <hip/hip_runtime.h>
#include <math.h>

#define H 128
#define NPB 16  // nodes per block in the GEMM pass

// ---- float atomic max via ordered-int trick (init must be -inf) ----
__device__ inline void atomicMaxF(float* addr, float v) {
    if (v >= 0.0f) {
        atomicMax((int*)addr, __float_as_int(v));
    } else {
        atomicMin((unsigned int*)addr, __float_as_uint(v));
    }
}

__global__ void init_kernel(float* smax, float* ssum, int n_nodes) {
    int i = blockIdx.x * blockDim.x + threadIdx.x;
    if (i < n_nodes) {
        smax[i] = -INFINITY;
        ssum[i] = 0.0f;
    }
}

// one wave (64 lanes) per edge: score = dot(ent[src]+rel[rid], ent[dst])
__global__ void score_kernel(const float* __restrict__ ent, const float* __restrict__ rel,
                             const int* __restrict__ src, const int* __restrict__ dst,
                             const int* __restrict__ rid,
                             float* __restrict__ score, float* __restrict__ smax, int n_edges) {
    int lane = threadIdx.x & 63;
    int e = blockIdx.x * (blockDim.x >> 6) + (threadIdx.x >> 6);
    if (e >= n_edges) return;
    int s = src[e], d = dst[e], r = rid[e];
    const float2* es = (const float2*)(ent + (size_t)s * H);
    const float2* rr = (const float2*)(rel + (size_t)r * H);
    const float2* ed = (const float2*)(ent + (size_t)d * H);
    float2 a = es[lane], b = rr[lane], c = ed[lane];
    float p = (a.x + b.x) * c.x + (a.y + b.y) * c.y;
    #pragma unroll
    for (int off = 32; off; off >>= 1)
        p += __shfl_xor(p, off, 64);
    if (lane == 0) {
        score[e] = p;
        atomicMaxF(&smax[d], p);
    }
}

// one thread per edge: ex = exp(score - smax[dst]); ssum[dst] += ex
__global__ void expsum_kernel(const int* __restrict__ dst, const float* __restrict__ smax,
                              float* __restrict__ score, float* __restrict__ ssum, int n_edges) {
    int e = blockIdx.x * blockDim.x + threadIdx.x;
    if (e >= n_edges) return;
    int d = dst[e];
    float ex = expf(score[e] - smax[d]);
    score[e] = ex;  // overwrite score with ex
    atomicAdd(&ssum[d], ex);
}

// one wave per edge: neigh[dst] += (ent[src]+rel[rid]) * (ex/ssum[dst])
__global__ void scatter_kernel(const float* __restrict__ ent, const float* __restrict__ rel,
                               const int* __restrict__ src, const int* __restrict__ dst,
                               const int* __restrict__ rid,
                               const float* __restrict__ ex, const float* __restrict__ ssum,
                               float* __restrict__ neigh, int n_edges) {
    int lane = threadIdx.x & 63;
    int e = blockIdx.x * (blockDim.x >> 6) + (threadIdx.x >> 6);
    if (e >= n_edges) return;
    int s = src[e], d = dst[e], r = rid[e];
    float norm = ex[e] / ssum[d];
    const float2* es = (const float2*)(ent + (size_t)s * H);
    const float2* rr = (const float2*)(rel + (size_t)r * H);
    float2 a = es[lane], b = rr[lane];
    float* out = neigh + (size_t)d * H;
    atomicAdd(&out[lane * 2],     (a.x + b.x) * norm);
    atomicAdd(&out[lane * 2 + 1], (a.y + b.y) * norm);
}

// out[n] = tanh(neigh[n] @ W), in-place on the node buffer.
// W staged in LDS once per block; NPB nodes per block.
__global__ __launch_bounds__(128) void mm_tanh_kernel(const float* __restrict__ W,
                                                      float* __restrict__ nodes, int n_nodes) {
    __shared__ float Ws[H * H];
    __shared__ float row[H];
    int t = threadIdx.x;
    for (int i = t; i < H * H; i += 128) Ws[i] = W[i];
    __syncthreads();
    int base = blockIdx.x * NPB;
    for (int j = 0; j < NPB; ++j) {
        int n = base + j;
        if (n >= n_nodes) break;
        row[t] = nodes[(size_t)n * H + t];
        __syncthreads();
        float acc = 0.0f;
        #pragma unroll 8
        for (int k = 0; k < H; ++k)
            acc += row[k] * Ws[k * H + t];
        nodes[(size_t)n * H + t] = tanhf(acc);
        __syncthreads();
    }
}

extern "C" void kernel_launch(void* const* d_in, const int* in_sizes, int n_in,
                              void* d_out, int out_size, void* d_ws, size_t ws_size,
                              hipStream_t stream) {
    const float* ent = (const float*)d_in[0];
    const float* rel = (const float*)d_in[1];
    const float* W   = (const float*)d_in[2];
    const int* src   = (const int*)d_in[3];
    const int* dst   = (const int*)d_in[4];
    const int* rid   = (const int*)d_in[5];
    int n_nodes = in_sizes[0] / H;
    int n_edges = in_sizes[3];
    float* out = (float*)d_out;

    // ws layout: smax[N] | ssum[N] | ex[E]
    float* smax = (float*)d_ws;
    float* ssum = smax + n_nodes;
    float* ex   = ssum + n_nodes;

    hipMemsetAsync(d_out, 0, (size_t)out_size * sizeof(float), stream);
    init_kernel<<<(n_nodes + 255) / 256, 256, 0, stream>>>(smax, ssum, n_nodes);

    const int wpb = 4;  // waves per block
    int blocks_e = (n_edges + wpb - 1) / wpb;
    score_kernel<<<blocks_e, wpb * 64, 0, stream>>>(ent, rel, src, dst, rid, ex, smax, n_edges);
    expsum_kernel<<<(n_edges + 255) / 256, 256, 0, stream>>>(dst, smax, ex, ssum, n_edges);
    scatter_kernel<<<blocks_e, wpb * 64, 0, stream>>>(ent, rel, src, dst, rid, ex, ssum, out, n_edges);
    mm_tanh_kernel<<<(n_nodes + NPB - 1) / NPB, 128, 0, stream>>>(W, out, n_nodes);
}

// Round 2
// 225.796 us; speedup vs baseline: 3.3811x; 3.3811x over previous
//
#include <hip/hip_runtime.h>
#include <math.h>

#define H 128
#define BLK 256
#define MM_ROWS 8
#define MM_TILES 4

// ---------- CSR build ----------
__global__ void zero2_kernel(int* a, int* b, int n) {
    int i = blockIdx.x * blockDim.x + threadIdx.x;
    if (i < n) { a[i] = 0; b[i] = 0; }
}

__global__ void count_kernel(const int* __restrict__ dst, int* __restrict__ cnt, int E) {
    int e = blockIdx.x * blockDim.x + threadIdx.x;
    if (e < E) atomicAdd(&cnt[dst[e]], 1);
}

__global__ void blocksum_kernel(const int* __restrict__ cnt, int* __restrict__ bsum, int n) {
    __shared__ int tmp[BLK];
    int i = blockIdx.x * BLK + threadIdx.x;
    tmp[threadIdx.x] = (i < n) ? cnt[i] : 0;
    __syncthreads();
    for (int d = BLK >> 1; d; d >>= 1) {
        if (threadIdx.x < d) tmp[threadIdx.x] += tmp[threadIdx.x + d];
        __syncthreads();
    }
    if (threadIdx.x == 0) bsum[blockIdx.x] = tmp[0];
}

// single-block exclusive scan of bsum[nb], nb <= BLK
__global__ void scanpart_kernel(int* bsum, int nb) {
    __shared__ int tmp[BLK];
    int t = threadIdx.x;
    int v = (t < nb) ? bsum[t] : 0;
    tmp[t] = v;
    __syncthreads();
    for (int d = 1; d < BLK; d <<= 1) {
        int add = (t >= d) ? tmp[t - d] : 0;
        __syncthreads();
        tmp[t] += add;
        __syncthreads();
    }
    if (t < nb) bsum[t] = tmp[t] - v;  // exclusive
}

__global__ void offsets_kernel(const int* __restrict__ cnt, const int* __restrict__ bsum,
                               int* __restrict__ off, int n, int E) {
    __shared__ int tmp[BLK];
    int t = threadIdx.x;
    int i = blockIdx.x * BLK + t;
    int v = (i < n) ? cnt[i] : 0;
    tmp[t] = v;
    __syncthreads();
    for (int d = 1; d < BLK; d <<= 1) {
        int add = (t >= d) ? tmp[t - d] : 0;
        __syncthreads();
        tmp[t] += add;
        __syncthreads();
    }
    if (i < n) off[i] = tmp[t] - v + bsum[blockIdx.x];
    if (i == 0) off[n] = E;
}

__global__ void fill_kernel(const int* __restrict__ src, const int* __restrict__ dst,
                            const int* __restrict__ rid, const int* __restrict__ off,
                            int* __restrict__ cursor, int2* __restrict__ epack, int E) {
    int e = blockIdx.x * blockDim.x + threadIdx.x;
    if (e >= E) return;
    int d = dst[e];
    int pos = atomicAdd(&cursor[d], 1);
    epack[off[d] + pos] = make_int2(src[e], rid[e]);
}

// ---------- fused gather: score + online softmax + weighted accumulate ----------
// one wave per node; writes the full neigh row (zeros for isolated nodes)
__global__ void gather_kernel(const float* __restrict__ ent, const float* __restrict__ rel,
                              const int2* __restrict__ epack, const int* __restrict__ off,
                              float* __restrict__ neigh, int n_nodes) {
    int lane = threadIdx.x & 63;
    int node = blockIdx.x * (blockDim.x >> 6) + (threadIdx.x >> 6);
    if (node >= n_nodes) return;
    int beg = off[node], end = off[node + 1];
    int deg = end - beg;
    float2 c = ((const float2*)(ent + (size_t)node * H))[lane];

    // prefetch edge list into lanes (deg <= 64 common case)
    int2 my = make_int2(0, 0);
    if (beg + lane < end) my = epack[beg + lane];

    float m = -INFINITY, s = 0.0f;
    float2 acc = make_float2(0.0f, 0.0f);
    for (int k = 0; k < deg; ++k) {
        int sv, rv;
        if (deg <= 64) {
            sv = __shfl(my.x, k, 64);
            rv = __shfl(my.y, k, 64);
        } else {
            int2 er = epack[beg + k];
            sv = er.x; rv = er.y;
        }
        float2 a = ((const float2*)(ent + (size_t)sv * H))[lane];
        float2 b = ((const float2*)(rel + (size_t)rv * H))[lane];
        float2 comp = make_float2(a.x + b.x, a.y + b.y);
        float p = comp.x * c.x + comp.y * c.y;
        #pragma unroll
        for (int o = 32; o; o >>= 1) p += __shfl_xor(p, o, 64);
        if (p > m) {  // online softmax rescale
            float f = __expf(m - p);
            s *= f; acc.x *= f; acc.y *= f;
            m = p;
        }
        float w = __expf(p - m);
        s += w;
        acc.x += comp.x * w;
        acc.y += comp.y * w;
    }
    float inv = (s > 0.0f) ? 1.0f / s : 0.0f;
    ((float2*)(neigh + (size_t)node * H))[lane] = make_float2(acc.x * inv, acc.y * inv);
}

// ---------- in-place tanh(neigh @ W) ----------
// 4-node register blocking; W staged once per block in LDS
__global__ __launch_bounds__(256) void mm_tanh_kernel(const float* __restrict__ W,
                                                      float* __restrict__ nodes, int n_nodes) {
    __shared__ float Ws[H * H];
    __shared__ float rows[MM_ROWS][H];
    int t = threadIdx.x;
    for (int i = t; i < H * H; i += 256) Ws[i] = W[i];
    int c = t & (H - 1);
    int g = t >> 7;  // 0..1
    for (int tile = 0; tile < MM_TILES; ++tile) {
        int base = (blockIdx.x * MM_TILES + tile) * MM_ROWS;
        __syncthreads();  // Ws ready (iter 0); rows from prev tile consumed
        for (int i = t; i < MM_ROWS * H; i += 256) {
            int n = base + (i >> 7);
            rows[i >> 7][i & (H - 1)] = (n < n_nodes) ? nodes[(size_t)n * H + (i & (H - 1))] : 0.0f;
        }
        __syncthreads();
        float acc0 = 0, acc1 = 0, acc2 = 0, acc3 = 0;
        #pragma unroll 4
        for (int k = 0; k < H; ++k) {
            float w = Ws[k * H + c];
            acc0 += rows[g * 4 + 0][k] * w;
            acc1 += rows[g * 4 + 1][k] * w;
            acc2 += rows[g * 4 + 2][k] * w;
            acc3 += rows[g * 4 + 3][k] * w;
        }
        int n0 = base + g * 4;
        if (n0 + 0 < n_nodes) nodes[(size_t)(n0 + 0) * H + c] = tanhf(acc0);
        if (n0 + 1 < n_nodes) nodes[(size_t)(n0 + 1) * H + c] = tanhf(acc1);
        if (n0 + 2 < n_nodes) nodes[(size_t)(n0 + 2) * H + c] = tanhf(acc2);
        if (n0 + 3 < n_nodes) nodes[(size_t)(n0 + 3) * H + c] = tanhf(acc3);
    }
}

extern "C" void kernel_launch(void* const* d_in, const int* in_sizes, int n_in,
                              void* d_out, int out_size, void* d_ws, size_t ws_size,
                              hipStream_t stream) {
    const float* ent = (const float*)d_in[0];
    const float* rel = (const float*)d_in[1];
    const float* W   = (const float*)d_in[2];
    const int* src   = (const int*)d_in[3];
    const int* dst   = (const int*)d_in[4];
    const int* rid   = (const int*)d_in[5];
    int n_nodes = in_sizes[0] / H;
    int n_edges = in_sizes[3];
    float* out = (float*)d_out;

    // ws layout (ints): cnt[N] | cursor[N] | off[N+1] | bsum[BLK] | epack[2E]
    int* cnt    = (int*)d_ws;
    int* cursor = cnt + n_nodes;
    int* off    = cursor + n_nodes;
    int* bsum   = off + n_nodes + 1;
    int2* epack = (int2*)(bsum + BLK);

    int nb1 = (n_nodes + BLK - 1) / BLK;  // 196 for N=50000, fits single-block scan

    zero2_kernel<<<nb1, BLK, 0, stream>>>(cnt, cursor, n_nodes);
    count_kernel<<<(n_edges + BLK - 1) / BLK, BLK, 0, stream>>>(dst, cnt, n_edges);
    blocksum_kernel<<<nb1, BLK, 0, stream>>>(cnt, bsum, n_nodes);
    scanpart_kernel<<<1, BLK, 0, stream>>>(bsum, nb1);
    offsets_kernel<<<nb1, BLK, 0, stream>>>(cnt, bsum, off, n_nodes, n_edges);
    fill_kernel<<<(n_edges + BLK - 1) / BLK, BLK, 0, stream>>>(src, dst, rid, off, cursor, epack, n_edges);

    const int wpb = 4;  // waves per block
    gather_kernel<<<(n_nodes + wpb - 1) / wpb, wpb * 64, 0, stream>>>(ent, rel, epack, off, out, n_nodes);

    mm_tanh_kernel<<<(n_nodes + MM_ROWS * MM_TILES - 1) / (MM_ROWS * MM_TILES), 256, 0, stream>>>(W, out, n_nodes);
}

// Round 3
// 175.140 us; speedup vs baseline: 4.3590x; 1.2892x over previous
//
#include <hip/hip_runtime.h>
#include <math.h>

#define H 128
#define BLK 256
#define MMR 64  // rows per block in the GEMM pass

__device__ inline float fast_tanh(float x) {
    // 1 - 2/(e^2x + 1); saturates correctly at +/-inf
    return 1.0f - 2.0f / (__expf(2.0f * x) + 1.0f);
}

// ---------- CSR build ----------
__global__ void zero2_kernel(int* a, int* b, int n) {
    int i = blockIdx.x * blockDim.x + threadIdx.x;
    if (i < n) { a[i] = 0; b[i] = 0; }
}

__global__ void count_kernel(const int* __restrict__ dst, int* __restrict__ cnt, int E) {
    int e = blockIdx.x * blockDim.x + threadIdx.x;
    if (e < E) atomicAdd(&cnt[dst[e]], 1);
}

__global__ void blocksum_kernel(const int* __restrict__ cnt, int* __restrict__ bsum, int n) {
    __shared__ int tmp[BLK];
    int i = blockIdx.x * BLK + threadIdx.x;
    tmp[threadIdx.x] = (i < n) ? cnt[i] : 0;
    __syncthreads();
    for (int d = BLK >> 1; d; d >>= 1) {
        if (threadIdx.x < d) tmp[threadIdx.x] += tmp[threadIdx.x + d];
        __syncthreads();
    }
    if (threadIdx.x == 0) bsum[blockIdx.x] = tmp[0];
}

// single-block exclusive scan of bsum[nb], nb <= BLK
__global__ void scanpart_kernel(int* bsum, int nb) {
    __shared__ int tmp[BLK];
    int t = threadIdx.x;
    int v = (t < nb) ? bsum[t] : 0;
    tmp[t] = v;
    __syncthreads();
    for (int d = 1; d < BLK; d <<= 1) {
        int add = (t >= d) ? tmp[t - d] : 0;
        __syncthreads();
        tmp[t] += add;
        __syncthreads();
    }
    if (t < nb) bsum[t] = tmp[t] - v;  // exclusive
}

__global__ void offsets_kernel(const int* __restrict__ cnt, const int* __restrict__ bsum,
                               int* __restrict__ off, int n, int E) {
    __shared__ int tmp[BLK];
    int t = threadIdx.x;
    int i = blockIdx.x * BLK + t;
    int v = (i < n) ? cnt[i] : 0;
    tmp[t] = v;
    __syncthreads();
    for (int d = 1; d < BLK; d <<= 1) {
        int add = (t >= d) ? tmp[t - d] : 0;
        __syncthreads();
        tmp[t] += add;
        __syncthreads();
    }
    if (i < n) off[i] = tmp[t] - v + bsum[blockIdx.x];
    if (i == 0) off[n] = E;
}

__global__ void fill_kernel(const int* __restrict__ src, const int* __restrict__ dst,
                            const int* __restrict__ rid, const int* __restrict__ off,
                            int* __restrict__ cursor, int2* __restrict__ epack, int E) {
    int e = blockIdx.x * blockDim.x + threadIdx.x;
    if (e >= E) return;
    int d = dst[e];
    int pos = atomicAdd(&cursor[d], 1);
    epack[off[d] + pos] = make_int2(src[e], rid[e]);
}

// ---------- fused gather: score + online softmax + weighted accumulate ----------
// one wave per node; writes the full neigh row (zeros for isolated nodes)
__global__ void gather_kernel(const float* __restrict__ ent, const float* __restrict__ rel,
                              const int2* __restrict__ epack, const int* __restrict__ off,
                              float* __restrict__ neigh, int n_nodes) {
    int lane = threadIdx.x & 63;
    int node = blockIdx.x * (blockDim.x >> 6) + (threadIdx.x >> 6);
    if (node >= n_nodes) return;
    int beg = off[node], end = off[node + 1];
    int deg = end - beg;
    float2 c = ((const float2*)(ent + (size_t)node * H))[lane];

    // prefetch edge list into lanes (deg <= 64 common case)
    int2 my = make_int2(0, 0);
    if (beg + lane < end) my = epack[beg + lane];

    float m = -INFINITY, s = 0.0f;
    float2 acc = make_float2(0.0f, 0.0f);
    for (int k = 0; k < deg; ++k) {
        int sv, rv;
        if (deg <= 64) {
            sv = __shfl(my.x, k, 64);
            rv = __shfl(my.y, k, 64);
        } else {
            int2 er = epack[beg + k];
            sv = er.x; rv = er.y;
        }
        float2 a = ((const float2*)(ent + (size_t)sv * H))[lane];
        float2 b = ((const float2*)(rel + (size_t)rv * H))[lane];
        float2 comp = make_float2(a.x + b.x, a.y + b.y);
        float p = comp.x * c.x + comp.y * c.y;
        #pragma unroll
        for (int o = 32; o; o >>= 1) p += __shfl_xor(p, o, 64);
        if (p > m) {  // online softmax rescale
            float f = __expf(m - p);
            s *= f; acc.x *= f; acc.y *= f;
            m = p;
        }
        float w = __expf(p - m);
        s += w;
        acc.x += comp.x * w;
        acc.y += comp.y * w;
    }
    float inv = (s > 0.0f) ? 1.0f / s : 0.0f;
    ((float2*)(neigh + (size_t)node * H))[lane] = make_float2(acc.x * inv, acc.y * inv);
}

// ---------- in-place tanh(neigh @ W) ----------
// 64 rows/block. Rows staged in LDS (32 KB); W streamed from global (L1/L2
// resident, 64 KB). Each thread: 8 rows x 4 cols register tile.
// Per 4-k chunk: 4 global float4 (W) + 8 ds_read_b128 (rows) -> 128 FMAs.
__global__ __launch_bounds__(256) void mm_tanh_kernel(const float* __restrict__ W,
                                                      float* __restrict__ nodes, int n_nodes) {
    __shared__ float rows[MMR][H];  // 32 KB
    int t = threadIdx.x;
    int base = blockIdx.x * MMR;
    // cooperative staging of the 64x128 row tile
    for (int i = t; i < MMR * (H / 4); i += 256) {
        int r = i >> 5;       // 32 float4 per row
        int c4 = i & 31;
        int n = base + r;
        float4 v = make_float4(0.f, 0.f, 0.f, 0.f);
        if (n < n_nodes) v = ((const float4*)(nodes + (size_t)n * H))[c4];
        ((float4*)rows[r])[c4] = v;
    }
    __syncthreads();

    int c0 = (t & 31) * 4;
    int r0 = (t >> 5) * 8;
    float acc[8][4] = {};
    #pragma unroll 2
    for (int k = 0; k < H; k += 4) {
        float4 w0 = *(const float4*)(W + (size_t)(k + 0) * H + c0);
        float4 w1 = *(const float4*)(W + (size_t)(k + 1) * H + c0);
        float4 w2 = *(const float4*)(W + (size_t)(k + 2) * H + c0);
        float4 w3 = *(const float4*)(W + (size_t)(k + 3) * H + c0);
        #pragma unroll
        for (int r = 0; r < 8; ++r) {
            float4 rv = *(const float4*)(&rows[r0 + r][k]);
            acc[r][0] += rv.x * w0.x + rv.y * w1.x + rv.z * w2.x + rv.w * w3.x;
            acc[r][1] += rv.x * w0.y + rv.y * w1.y + rv.z * w2.y + rv.w * w3.y;
            acc[r][2] += rv.x * w0.z + rv.y * w1.z + rv.z * w2.z + rv.w * w3.z;
            acc[r][3] += rv.x * w0.w + rv.y * w1.w + rv.z * w2.w + rv.w * w3.w;
        }
    }
    #pragma unroll
    for (int r = 0; r < 8; ++r) {
        int n = base + r0 + r;
        if (n < n_nodes) {
            float4 o;
            o.x = fast_tanh(acc[r][0]);
            o.y = fast_tanh(acc[r][1]);
            o.z = fast_tanh(acc[r][2]);
            o.w = fast_tanh(acc[r][3]);
            *(float4*)(nodes + (size_t)n * H + c0) = o;
        }
    }
}

extern "C" void kernel_launch(void* const* d_in, const int* in_sizes, int n_in,
                              void* d_out, int out_size, void* d_ws, size_t ws_size,
                              hipStream_t stream) {
    const float* ent = (const float*)d_in[0];
    const float* rel = (const float*)d_in[1];
    const float* W   = (const float*)d_in[2];
    const int* src   = (const int*)d_in[3];
    const int* dst   = (const int*)d_in[4];
    const int* rid   = (const int*)d_in[5];
    int n_nodes = in_sizes[0] / H;
    int n_edges = in_sizes[3];
    float* out = (float*)d_out;

    // ws layout (ints): cnt[N] | cursor[N] | off[N+1] | bsum[BLK] | epack[2E]
    int* cnt    = (int*)d_ws;
    int* cursor = cnt + n_nodes;
    int* off    = cursor + n_nodes;
    int* bsum   = off + n_nodes + 1;
    int2* epack = (int2*)(bsum + BLK);

    int nb1 = (n_nodes + BLK - 1) / BLK;  // 196 for N=50000, fits single-block scan

    zero2_kernel<<<nb1, BLK, 0, stream>>>(cnt, cursor, n_nodes);
    count_kernel<<<(n_edges + BLK - 1) / BLK, BLK, 0, stream>>>(dst, cnt, n_edges);
    blocksum_kernel<<<nb1, BLK, 0, stream>>>(cnt, bsum, n_nodes);
    scanpart_kernel<<<1, BLK, 0, stream>>>(bsum, nb1);
    offsets_kernel<<<nb1, BLK, 0, stream>>>(cnt, bsum, off, n_nodes, n_edges);
    fill_kernel<<<(n_edges + BLK - 1) / BLK, BLK, 0, stream>>>(src, dst, rid, off, cursor, epack, n_edges);

    const int wpb = 4;  // waves per block
    gather_kernel<<<(n_nodes + wpb - 1) / wpb, wpb * 64, 0, stream>>>(ent, rel, epack, off, out, n_nodes);

    mm_tanh_kernel<<<(n_nodes + MMR - 1) / MMR, 256, 0, stream>>>(W, out, n_nodes);
}

// Round 4
// 154.880 us; speedup vs baseline: 4.9291x; 1.1308x over previous
//
#include <hip/hip_runtime.h>
#include <math.h>

#define H 128
#define BLK 256
#define MMR 64  // rows per block in the GEMM pass

__device__ inline float fast_tanh(float x) {
    return 1.0f - 2.0f / (__expf(2.0f * x) + 1.0f);
}

// ---------- CSR build ----------
__global__ void zero2_kernel(int* a, int* b, int n) {
    int i = blockIdx.x * blockDim.x + threadIdx.x;
    if (i < n) { a[i] = 0; b[i] = 0; }
}

__global__ void count_kernel(const int* __restrict__ dst, int* __restrict__ cnt, int E) {
    int e = blockIdx.x * blockDim.x + threadIdx.x;
    if (e < E) atomicAdd(&cnt[dst[e]], 1);
}

__global__ void blocksum_kernel(const int* __restrict__ cnt, int* __restrict__ bsum, int n) {
    __shared__ int tmp[BLK];
    int i = blockIdx.x * BLK + threadIdx.x;
    tmp[threadIdx.x] = (i < n) ? cnt[i] : 0;
    __syncthreads();
    for (int d = BLK >> 1; d; d >>= 1) {
        if (threadIdx.x < d) tmp[threadIdx.x] += tmp[threadIdx.x + d];
        __syncthreads();
    }
    if (threadIdx.x == 0) bsum[blockIdx.x] = tmp[0];
}

__global__ void scanpart_kernel(int* bsum, int nb) {
    __shared__ int tmp[BLK];
    int t = threadIdx.x;
    int v = (t < nb) ? bsum[t] : 0;
    tmp[t] = v;
    __syncthreads();
    for (int d = 1; d < BLK; d <<= 1) {
        int add = (t >= d) ? tmp[t - d] : 0;
        __syncthreads();
        tmp[t] += add;
        __syncthreads();
    }
    if (t < nb) bsum[t] = tmp[t] - v;  // exclusive
}

__global__ void offsets_kernel(const int* __restrict__ cnt, const int* __restrict__ bsum,
                               int* __restrict__ off, int n, int E) {
    __shared__ int tmp[BLK];
    int t = threadIdx.x;
    int i = blockIdx.x * BLK + t;
    int v = (i < n) ? cnt[i] : 0;
    tmp[t] = v;
    __syncthreads();
    for (int d = 1; d < BLK; d <<= 1) {
        int add = (t >= d) ? tmp[t - d] : 0;
        __syncthreads();
        tmp[t] += add;
        __syncthreads();
    }
    if (i < n) off[i] = tmp[t] - v + bsum[blockIdx.x];
    if (i == 0) off[n] = E;
}

__global__ void fill_kernel(const int* __restrict__ src, const int* __restrict__ dst,
                            const int* __restrict__ rid, const int* __restrict__ off,
                            int* __restrict__ cursor, int2* __restrict__ epack, int E) {
    int e = blockIdx.x * blockDim.x + threadIdx.x;
    if (e >= E) return;
    int d = dst[e];
    int pos = atomicAdd(&cursor[d], 1);
    epack[off[d] + pos] = make_int2(src[e], rid[e]);
}

// ---------- fused gather: 4 edges in flight per wave ----------
// wave = 4 groups x 16 lanes; each group owns one edge (float8 per lane).
// Per-group online softmax state, exact rescaled merge at the end.
__global__ void gather_kernel(const float* __restrict__ ent, const float* __restrict__ rel,
                              const int2* __restrict__ epack, const int* __restrict__ off,
                              float* __restrict__ neigh, int n_nodes) {
    int lane = threadIdx.x & 63;
    int node = blockIdx.x * (blockDim.x >> 6) + (threadIdx.x >> 6);
    if (node >= n_nodes) return;
    int beg = off[node];
    int deg = off[node + 1] - beg;
    int g = lane >> 4;   // group 0..3
    int gl = lane & 15;  // lane within group: columns gl*8 .. gl*8+7

    const float4* crow = (const float4*)(ent + (size_t)node * H);
    float4 c0 = crow[gl * 2], c1 = crow[gl * 2 + 1];

    float m = -3.0e38f, s = 0.0f;
    float4 acc0 = make_float4(0.f, 0.f, 0.f, 0.f);
    float4 acc1 = make_float4(0.f, 0.f, 0.f, 0.f);

    for (int base = 0; base < deg; base += 64) {
        int chunk = min(64, deg - base);
        int2 my = make_int2(0, 0);
        if (lane < chunk) my = epack[beg + base + lane];
        int iters = (chunk + 3) >> 2;
        for (int i = 0; i < iters; ++i) {
            int k = i * 4 + g;           // this group's edge
            bool valid = k < chunk;
            int kk = valid ? k : 0;
            int sv = __shfl(my.x, kk, 64);
            int rv = __shfl(my.y, kk, 64);
            if (valid) {
                const float4* ar = (const float4*)(ent + (size_t)sv * H);
                const float4* br = (const float4*)(rel + (size_t)rv * H);
                float4 a0 = ar[gl * 2], a1 = ar[gl * 2 + 1];
                float4 b0 = br[gl * 2], b1 = br[gl * 2 + 1];
                float4 q0, q1;
                q0.x = a0.x + b0.x; q0.y = a0.y + b0.y; q0.z = a0.z + b0.z; q0.w = a0.w + b0.w;
                q1.x = a1.x + b1.x; q1.y = a1.y + b1.y; q1.z = a1.z + b1.z; q1.w = a1.w + b1.w;
                float p = q0.x * c0.x + q0.y * c0.y + q0.z * c0.z + q0.w * c0.w
                        + q1.x * c1.x + q1.y * c1.y + q1.z * c1.z + q1.w * c1.w;
                // reduce within the 16-lane group
                p += __shfl_xor(p, 1, 64);
                p += __shfl_xor(p, 2, 64);
                p += __shfl_xor(p, 4, 64);
                p += __shfl_xor(p, 8, 64);
                if (p > m) {
                    float f = __expf(m - p);
                    s *= f;
                    acc0.x *= f; acc0.y *= f; acc0.z *= f; acc0.w *= f;
                    acc1.x *= f; acc1.y *= f; acc1.z *= f; acc1.w *= f;
                    m = p;
                }
                float w = __expf(p - m);
                s += w;
                acc0.x += q0.x * w; acc0.y += q0.y * w; acc0.z += q0.z * w; acc0.w += q0.w * w;
                acc1.x += q1.x * w; acc1.y += q1.y * w; acc1.z += q1.z * w; acc1.w += q1.w * w;
            }
        }
    }

    // merge the 4 group states (exact, rescaled); empty groups have m=-3e38,s=0
    #pragma unroll
    for (int xo = 16; xo <= 32; xo <<= 1) {
        float om = __shfl_xor(m, xo, 64);
        float os = __shfl_xor(s, xo, 64);
        float4 oa0, oa1;
        oa0.x = __shfl_xor(acc0.x, xo, 64); oa0.y = __shfl_xor(acc0.y, xo, 64);
        oa0.z = __shfl_xor(acc0.z, xo, 64); oa0.w = __shfl_xor(acc0.w, xo, 64);
        oa1.x = __shfl_xor(acc1.x, xo, 64); oa1.y = __shfl_xor(acc1.y, xo, 64);
        oa1.z = __shfl_xor(acc1.z, xo, 64); oa1.w = __shfl_xor(acc1.w, xo, 64);
        float M = fmaxf(m, om);
        float fs = __expf(m - M), fo = __expf(om - M);
        s = s * fs + os * fo;
        acc0.x = acc0.x * fs + oa0.x * fo; acc0.y = acc0.y * fs + oa0.y * fo;
        acc0.z = acc0.z * fs + oa0.z * fo; acc0.w = acc0.w * fs + oa0.w * fo;
        acc1.x = acc1.x * fs + oa1.x * fo; acc1.y = acc1.y * fs + oa1.y * fo;
        acc1.z = acc1.z * fs + oa1.z * fo; acc1.w = acc1.w * fs + oa1.w * fo;
        m = M;
    }
    float inv = (s > 0.0f) ? 1.0f / s : 0.0f;
    if (g == 0) {
        float4 o0 = make_float4(acc0.x * inv, acc0.y * inv, acc0.z * inv, acc0.w * inv);
        float4 o1 = make_float4(acc1.x * inv, acc1.y * inv, acc1.z * inv, acc1.w * inv);
        float4* outr = (float4*)(neigh + (size_t)node * H);
        outr[gl * 2] = o0;
        outr[gl * 2 + 1] = o1;
    }
}

// ---------- in-place tanh(neigh @ W) ----------
__global__ __launch_bounds__(256) void mm_tanh_kernel(const float* __restrict__ W,
                                                      float* __restrict__ nodes, int n_nodes) {
    __shared__ float rows[MMR][H];  // 32 KB
    int t = threadIdx.x;
    int base = blockIdx.x * MMR;
    for (int i = t; i < MMR * (H / 4); i += 256) {
        int r = i >> 5;
        int c4 = i & 31;
        int n = base + r;
        float4 v = make_float4(0.f, 0.f, 0.f, 0.f);
        if (n < n_nodes) v = ((const float4*)(nodes + (size_t)n * H))[c4];
        ((float4*)rows[r])[c4] = v;
    }
    __syncthreads();

    int c0 = (t & 31) * 4;
    int r0 = (t >> 5) * 8;
    float acc[8][4] = {};
    #pragma unroll 2
    for (int k = 0; k < H; k += 4) {
        float4 w0 = *(const float4*)(W + (size_t)(k + 0) * H + c0);
        float4 w1 = *(const float4*)(W + (size_t)(k + 1) * H + c0);
        float4 w2 = *(const float4*)(W + (size_t)(k + 2) * H + c0);
        float4 w3 = *(const float4*)(W + (size_t)(k + 3) * H + c0);
        #pragma unroll
        for (int r = 0; r < 8; ++r) {
            float4 rv = *(const float4*)(&rows[r0 + r][k]);
            acc[r][0] += rv.x * w0.x + rv.y * w1.x + rv.z * w2.x + rv.w * w3.x;
            acc[r][1] += rv.x * w0.y + rv.y * w1.y + rv.z * w2.y + rv.w * w3.y;
            acc[r][2] += rv.x * w0.z + rv.y * w1.z + rv.z * w2.z + rv.w * w3.z;
            acc[r][3] += rv.x * w0.w + rv.y * w1.w + rv.z * w2.w + rv.w * w3.w;
        }
    }
    #pragma unroll
    for (int r = 0; r < 8; ++r) {
        int n = base + r0 + r;
        if (n < n_nodes) {
            float4 o;
            o.x = fast_tanh(acc[r][0]);
            o.y = fast_tanh(acc[r][1]);
            o.z = fast_tanh(acc[r][2]);
            o.w = fast_tanh(acc[r][3]);
            *(float4*)(nodes + (size_t)n * H + c0) = o;
        }
    }
}

extern "C" void kernel_launch(void* const* d_in, const int* in_sizes, int n_in,
                              void* d_out, int out_size, void* d_ws, size_t ws_size,
                              hipStream_t stream) {
    const float* ent = (const float*)d_in[0];
    const float* rel = (const float*)d_in[1];
    const float* W   = (const float*)d_in[2];
    const int* src   = (const int*)d_in[3];
    const int* dst   = (const int*)d_in[4];
    const int* rid   = (const int*)d_in[5];
    int n_nodes = in_sizes[0] / H;
    int n_edges = in_sizes[3];
    float* out = (float*)d_out;

    // ws layout (ints): cnt[N] | cursor[N] | off[N+1] | bsum[BLK] | epack[2E]
    int* cnt    = (int*)d_ws;
    int* cursor = cnt + n_nodes;
    int* off    = cursor + n_nodes;
    int* bsum   = off + n_nodes + 1;
    int2* epack = (int2*)(bsum + BLK);

    int nb1 = (n_nodes + BLK - 1) / BLK;

    zero2_kernel<<<nb1, BLK, 0, stream>>>(cnt, cursor, n_nodes);
    count_kernel<<<(n_edges + BLK - 1) / BLK, BLK, 0, stream>>>(dst, cnt, n_edges);
    blocksum_kernel<<<nb1, BLK, 0, stream>>>(cnt, bsum, n_nodes);
    scanpart_kernel<<<1, BLK, 0, stream>>>(bsum, nb1);
    offsets_kernel<<<nb1, BLK, 0, stream>>>(cnt, bsum, off, n_nodes, n_edges);
    fill_kernel<<<(n_edges + BLK - 1) / BLK, BLK, 0, stream>>>(src, dst, rid, off, cursor, epack, n_edges);

    const int wpb = 4;
    gather_kernel<<<(n_nodes + wpb - 1) / wpb, wpb * 64, 0, stream>>>(ent, rel, epack, off, out, n_nodes);

    mm_tanh_kernel<<<(n_nodes + MMR - 1) / MMR, 256, 0, stream>>>(W, out, n_nodes);
}